// Round 8
// baseline (164.018 us; speedup 1.0000x reference)
//
#include <hip/hip_runtime.h>
#include <stdint.h>

#define B_SZ 2
#define T_SZ 2048
#define C_SZ 1024
#define NH   16
#define NKV  4
#define HD   64
#define KVD  256
#define QKV_N 1536

typedef __attribute__((ext_vector_type(8))) short bf16x8;
typedef __attribute__((ext_vector_type(4))) float f32x4;
typedef __attribute__((ext_vector_type(16))) float f32x16;

#define GL(p) ((const __attribute__((address_space(1))) void*)(p))
#define LD(p) ((__attribute__((address_space(3))) void*)(p))

__device__ inline unsigned short f2bf(float f) {
  union { float f; unsigned u; } v; v.f = f;
  unsigned u = v.u;
  unsigned r = (u + 0x7fffu + ((u >> 16) & 1u)) >> 16;
  return (unsigned short)r;
}
__device__ inline unsigned cvtpk_bf16(float lo, float hi_) {  // D.lo=cvt(S0), D.hi=cvt(S1)
  unsigned r;
  asm("v_cvt_pk_bf16_f32 %0, %1, %2" : "=v"(r) : "v"(lo), "v"(hi_));
  return r;
}

// ---------------- fused fp32->bf16 convert (5 segments) + gate precompute, 1 launch ----------------
struct CvtArgs {
  const float *s0, *s1, *s2, *s3, *s4;
  unsigned short *d0, *d1, *d2, *d3, *d4;
  const float *x, *Wg;
  float *gate;           // [B*T][NKV]
};
__global__ __launch_bounds__(256) void cvt_all(CvtArgs a) {
  int blk = blockIdx.x, tid = threadIdx.x;
  if (blk >= 6656) {  // gate: 3*sigmoid(x[:, :12] @ Wg^T)
    int idx = (blk - 6656) * 256 + tid;
    int bt = idx >> 2, kh = idx & 3;
    float s = 0.f;
#pragma unroll
    for (int j = 0; j < 12; j++) s += a.x[(size_t)bt * C_SZ + j] * a.Wg[kh * 12 + j];
    a.gate[idx] = 3.f / (1.f + __expf(-s));
    return;
  }
  const float* s; unsigned short* d; int i;
  if      (blk < 4096) { s = a.s0; d = a.d0; i = blk * 256 + tid; }
  else if (blk < 5120) { s = a.s1; d = a.d1; i = (blk - 4096) * 256 + tid; }
  else if (blk < 5376) { s = a.s2; d = a.d2; i = (blk - 5120) * 256 + tid; }
  else if (blk < 5632) { s = a.s3; d = a.d3; i = (blk - 5376) * 256 + tid; }
  else                 { s = a.s4; d = a.d4; i = (blk - 5632) * 256 + tid; }
  float4 f = ((const float4*)s)[i];
  ushort4 o;
  o.x = f2bf(f.x); o.y = f2bf(f.y); o.z = f2bf(f.z); o.w = f2bf(f.w);
  ((ushort4*)d)[i] = o;
}

// ========== GEMM core: 64x128 tile, BK=64, single-barrier ping-pong dbuf, XOR-swizzled LDS ==========
#define GEMM_PROLOG(A, Bm, K)                                                        \
  __shared__ unsigned short As[2][64 * 64];                                          \
  __shared__ unsigned short Bs[2][128 * 64];                                         \
  int tid  = threadIdx.x;                                                            \
  int lane = tid & 63;                                                               \
  int wave = tid >> 6;                                                               \
  int quad = lane >> 4;                                                              \
  int l16  = lane & 15;                                                              \
  int m0 = blockIdx.y * 64;                                                          \
  int n0 = blockIdx.x * 128;                                                         \
  int wm = (wave & 1) * 32;                                                          \
  int wn = (wave >> 1) * 64;                                                         \
  f32x4 acc[2][4];                                                                   \
  _Pragma("unroll") for (int i = 0; i < 2; i++)                                      \
    _Pragma("unroll") for (int j = 0; j < 4; j++)                                    \
      acc[i][j] = (f32x4){0.f, 0.f, 0.f, 0.f};                                       \
  int lrow = lane >> 3;                              /* 0..7 within 8-row block */   \
  int lcol = ((lane & 7) ^ lrow) * 8;                /* XOR-swizzled source chunk */ \
  int sA = wave * 16;                                                                \
  int sB = wave * 32;                                                                \
  const unsigned short* aP0 = &A[(size_t)(m0 + sA + lrow) * K + lcol];               \
  const unsigned short* aP1 = aP0 + 8 * (size_t)K;                                   \
  const unsigned short* bP0 = &Bm[(size_t)(n0 + sB + lrow) * K + lcol];              \
  const unsigned short* bP1 = bP0 + 8 * (size_t)K;                                   \
  const unsigned short* bP2 = bP0 + 16 * (size_t)K;                                  \
  const unsigned short* bP3 = bP0 + 24 * (size_t)K;                                  \
  __builtin_amdgcn_global_load_lds(GL(aP0), LD(&As[0][(sA     ) * 64]), 16, 0, 0);   \
  __builtin_amdgcn_global_load_lds(GL(aP1), LD(&As[0][(sA +  8) * 64]), 16, 0, 0);   \
  __builtin_amdgcn_global_load_lds(GL(bP0), LD(&Bs[0][(sB     ) * 64]), 16, 0, 0);   \
  __builtin_amdgcn_global_load_lds(GL(bP1), LD(&Bs[0][(sB +  8) * 64]), 16, 0, 0);   \
  __builtin_amdgcn_global_load_lds(GL(bP2), LD(&Bs[0][(sB + 16) * 64]), 16, 0, 0);   \
  __builtin_amdgcn_global_load_lds(GL(bP3), LD(&Bs[0][(sB + 24) * 64]), 16, 0, 0);   \
  int swz = l16 & 7;                                                                 \
  int nk = K >> 6;                                                                   \
  for (int ki = 0; ki < nk; ki++) {                                                  \
    int cur = ki & 1, nxt = cur ^ 1;                                                 \
    __syncthreads();                                                                 \
    if (ki + 1 < nk) {                                                               \
      int k0 = (ki + 1) << 6;                                                        \
      __builtin_amdgcn_global_load_lds(GL(aP0 + k0), LD(&As[nxt][(sA     ) * 64]), 16, 0, 0); \
      __builtin_amdgcn_global_load_lds(GL(aP1 + k0), LD(&As[nxt][(sA +  8) * 64]), 16, 0, 0); \
      __builtin_amdgcn_global_load_lds(GL(bP0 + k0), LD(&Bs[nxt][(sB     ) * 64]), 16, 0, 0); \
      __builtin_amdgcn_global_load_lds(GL(bP1 + k0), LD(&Bs[nxt][(sB +  8) * 64]), 16, 0, 0); \
      __builtin_amdgcn_global_load_lds(GL(bP2 + k0), LD(&Bs[nxt][(sB + 16) * 64]), 16, 0, 0); \
      __builtin_amdgcn_global_load_lds(GL(bP3 + k0), LD(&Bs[nxt][(sB + 24) * 64]), 16, 0, 0); \
    }                                                                                \
    _Pragma("unroll") for (int p = 0; p < 2; p++) {                                  \
      bf16x8 af[2], bfr[4];                                                          \
      _Pragma("unroll") for (int i = 0; i < 2; i++)                                  \
        af[i] = *(const bf16x8*)&As[cur][(wm + i * 16 + l16) * 64 + (((p * 4 + quad) ^ swz) * 8)]; \
      _Pragma("unroll") for (int j = 0; j < 4; j++)                                  \
        bfr[j] = *(const bf16x8*)&Bs[cur][(wn + j * 16 + l16) * 64 + (((p * 4 + quad) ^ swz) * 8)]; \
      _Pragma("unroll") for (int i = 0; i < 2; i++)                                  \
        _Pragma("unroll") for (int j = 0; j < 4; j++)                                \
          acc[i][j] = __builtin_amdgcn_mfma_f32_16x16x32_bf16(af[i], bfr[j], acc[i][j], 0, 0, 0); \
    }                                                                                \
  }

// ---------------- gemm2: C[m,n] = sum_k A[m,k]*B[n,k], fp32 out ----------------
__global__ __launch_bounds__(256) void gemm_bt(const unsigned short* __restrict__ A,
                                               const unsigned short* __restrict__ Bm,
                                               float* __restrict__ C,
                                               int N, int K) {
  GEMM_PROLOG(A, Bm, K)
#pragma unroll
  for (int i = 0; i < 2; i++) {
#pragma unroll
    for (int j = 0; j < 4; j++) {
      int col = n0 + wn + j * 16 + l16;
#pragma unroll
      for (int r = 0; r < 4; r++) {
        int row = m0 + wm + i * 16 + quad * 4 + r;
        C[(size_t)row * N + col] = acc[i][j][r];
      }
    }
  }
}

// ---------------- gemm1 fused: qkv proj + RoPE + RMSNorm + gate*ve + V-TRANSPOSE, bf16 out ----------
__global__ __launch_bounds__(256) void gemm_qkv(const unsigned short* __restrict__ A,
                                                const unsigned short* __restrict__ Bm,
                                                const float* __restrict__ ve,
                                                const float* __restrict__ cosb,
                                                const float* __restrict__ sinb,
                                                const float* __restrict__ gateArr,
                                                unsigned short* __restrict__ qa,
                                                unsigned short* __restrict__ ka,
                                                unsigned short* __restrict__ vt) {
  const int K = C_SZ;
  GEMM_PROLOG(A, Bm, K)

  int colbase = n0 + wn;   // multiple of 64
  if (colbase < 1280) {    // Q or K head
    int isQ = colbase < 1024;
    int h   = isQ ? (colbase >> 6) : ((colbase - 1024) >> 6);
    float scale = isQ ? (0.15f * 1.44269504088896f) : 1.2f;
    unsigned short* dst = isQ ? qa : ka;
    int nheads = isQ ? NH : NKV;
#pragma unroll
    for (int i = 0; i < 2; i++) {
#pragma unroll
      for (int r = 0; r < 4; r++) {
        int row = m0 + wm + i * 16 + quad * 4 + r;   // bt
        int t = row & (T_SZ - 1), b = row >> 11;
        float a10 = acc[i][0][r], a11 = acc[i][1][r];
        float a20 = acc[i][2][r], a21 = acc[i][3][r];
        float cv0 = cosb[t * 32 + l16],      sv0 = sinb[t * 32 + l16];
        float cv1 = cosb[t * 32 + 16 + l16], sv1 = sinb[t * 32 + 16 + l16];
        float o10 =  a10 * cv0 + a20 * sv0;
        float o11 =  a11 * cv1 + a21 * sv1;
        float o20 = -a10 * sv0 + a20 * cv0;
        float o21 = -a11 * sv1 + a21 * cv1;
        float ssq = o10 * o10 + o11 * o11 + o20 * o20 + o21 * o21;
        ssq += __shfl_xor(ssq, 1);
        ssq += __shfl_xor(ssq, 2);
        ssq += __shfl_xor(ssq, 4);
        ssq += __shfl_xor(ssq, 8);
        float rn = rsqrtf(ssq * (1.f / 64.f) + 1e-6f) * scale;
        size_t base = ((size_t)(b * nheads + h) * T_SZ + t) * HD;
        dst[base + l16]      = f2bf(o10 * rn);
        dst[base + 16 + l16] = f2bf(o11 * rn);
        dst[base + 32 + l16] = f2bf(o20 * rn);
        dst[base + 48 + l16] = f2bf(o21 * rn);
      }
    }
  } else {                 // V block: gate*ve add, transpose via LDS, write vt directly
    int kh  = (colbase - 1280) >> 6;                 // this wave's head
    int khb = (n0 - 1280) >> 6;                      // block's base head
    unsigned short* tile = (unsigned short*)&Bs[0][0];   // 64 x 128, stride 132
    const int TS = 132;
#pragma unroll
    for (int i = 0; i < 2; i++) {
#pragma unroll
      for (int r = 0; r < 4; r++) {
        int rl  = wm + i * 16 + quad * 4 + r;        // t_local 0..63
        int row = m0 + rl;                           // bt
        float g = gateArr[row * 4 + kh];
#pragma unroll
        for (int j = 0; j < 4; j++) {
          int d = j * 16 + l16;
          float val = acc[i][j][r] + g * ve[(size_t)row * KVD + kh * HD + d];
          tile[rl * TS + wn + d] = f2bf(val);
        }
      }
    }
    __syncthreads();
    int d2  = tid & 127;                             // 0..127 across both heads
    int seg = tid >> 7;                              // t half: 0,1
    int khw = khb + (d2 >> 6);
    int dd  = d2 & 63;
    int bb  = m0 >> 11;
    int tl0 = (m0 & (T_SZ - 1)) + seg * 32;
    unsigned short* dstp = &vt[((size_t)(bb * NKV + khw) * HD + dd) * T_SZ + tl0];
#pragma unroll
    for (int k4 = 0; k4 < 8; k4++) {
      ushort4 o;
      o.x = tile[(seg * 32 + k4 * 4 + 0) * TS + d2];
      o.y = tile[(seg * 32 + k4 * 4 + 1) * TS + d2];
      o.z = tile[(seg * 32 + k4 * 4 + 2) * TS + d2];
      o.w = tile[(seg * 32 + k4 * 4 + 3) * TS + d2];
      *(ushort4*)(dstp + k4 * 4) = o;
    }
  }
}

// ---------------- causal flash attention: 32x32 MFMA, in-register P (no P-LDS) ----------------
// 4 waves x 32 q-rows (Q=128/block). S^T = K*Q^T via mfma_32x32x16: lane holds col q=l32
// (FIXED), rows t=(reg&3)+8(reg>>2)+4hi. PV A-operand needs A[q=l32][t=16c+8hi+j] -> same
// lane m-index; t-halves exchanged in-register via v_cvt_pk_bf16_f32 + v_permlane32_swap_b32
// (2 swaps/chunk). Row-sum l via VALU accumulation + one final swap. K/V dbuf staged, KST=72
// (144B rows: 16B-aligned, banks spread 4/row -> conflict-free).
#define KST 72
__global__ __launch_bounds__(256) void attn(const unsigned short* __restrict__ qa,
                                            const unsigned short* __restrict__ ka,
                                            const unsigned short* __restrict__ vt,
                                            unsigned short* __restrict__ y) {
  int bid = blockIdx.x;
  int half = bid >> 8, r = bid & 255;
  int qt = half ? (r & 15) : 15 - (r & 15);
  int bh = (half << 4) | (r >> 4);
  int b = bh >> 4, h = bh & 15;
  int kh = h >> 2;
  int tid = threadIdx.x;
  int wave = tid >> 6, lane = tid & 63;
  int l32 = lane & 31, hi = lane >> 5;

  __shared__ unsigned short Ks[2][64 * KST];   // [t_local][d]
  __shared__ unsigned short Vs[2][64 * KST];   // [d][t_local]
  __shared__ float Ls[4][32];                  // per-wave row-sum redistribute

  int qrow0 = qt * 128 + wave * 32;

  // Q B-frags: B[k=d][n=q], lane holds Q[qrow0+l32][d = kc*16 + hi*8 + j]
  bf16x8 bq[4];
  {
    const unsigned short* qp = &qa[((size_t)(b * NH + h) * T_SZ + qrow0 + l32) * HD + hi * 8];
    bq[0] = *(const bf16x8*)(qp);
    bq[1] = *(const bf16x8*)(qp + 16);
    bq[2] = *(const bf16x8*)(qp + 32);
    bq[3] = *(const bf16x8*)(qp + 48);
  }

  f32x16 oacc0, oacc1;
#pragma unroll
  for (int i = 0; i < 16; i++) { oacc0[i] = 0.f; oacc1[i] = 0.f; }
  float lsum = 0.f;

  // staging: 256 threads, 64 rows x 8 chunks, 2x uint4 per thread
  int lr   = tid >> 2;
  int gcol = (tid & 3) * 16;

  const unsigned short* kbase = &ka[(size_t)(b * NKV + kh) * T_SZ * HD];
  const unsigned short* vbase = &vt[(size_t)(b * NKV + kh) * HD * T_SZ];

  int nj = 2 * qt + 2;

  {
    uint4 k0 = *(const uint4*)&kbase[(size_t)lr * HD + gcol];
    uint4 k1 = *(const uint4*)&kbase[(size_t)lr * HD + gcol + 8];
    uint4 v0 = *(const uint4*)&vbase[(size_t)lr * T_SZ + gcol];
    uint4 v1 = *(const uint4*)&vbase[(size_t)lr * T_SZ + gcol + 8];
    *(uint4*)&Ks[0][lr * KST + gcol]     = k0;
    *(uint4*)&Ks[0][lr * KST + gcol + 8] = k1;
    *(uint4*)&Vs[0][lr * KST + gcol]     = v0;
    *(uint4*)&Vs[0][lr * KST + gcol + 8] = v1;
  }

  for (int j = 0; j < nj; j++) {
    int cur = j & 1, nxt = cur ^ 1;
    __syncthreads();

    uint4 k0, k1, v0, v1;
    bool pf = (j + 1 < nj);
    if (pf) {
      k0 = *(const uint4*)&kbase[(size_t)((j + 1) * 64 + lr) * HD + gcol];
      k1 = *(const uint4*)&kbase[(size_t)((j + 1) * 64 + lr) * HD + gcol + 8];
      v0 = *(const uint4*)&vbase[(size_t)lr * T_SZ + (j + 1) * 64 + gcol];
      v1 = *(const uint4*)&vbase[(size_t)lr * T_SZ + (j + 1) * 64 + gcol + 8];
    }

    bool active = (j * 64) <= (qrow0 + 31);
    if (active) {
      // QK: S^T[t][q], A = K (A[t=l32(+32sub)][k=hi*8+j]), B = bq
      f32x16 st0, st1;
#pragma unroll
      for (int i = 0; i < 16; i++) { st0[i] = 0.f; st1[i] = 0.f; }
      __builtin_amdgcn_s_setprio(1);
#pragma unroll
      for (int kc = 0; kc < 4; kc++) {
        bf16x8 ak0 = *(const bf16x8*)&Ks[cur][(l32)      * KST + kc * 16 + hi * 8];
        bf16x8 ak1 = *(const bf16x8*)&Ks[cur][(32 + l32) * KST + kc * 16 + hi * 8];
        st0 = __builtin_amdgcn_mfma_f32_32x32x16_bf16(ak0, bq[kc], st0, 0, 0, 0);
        st1 = __builtin_amdgcn_mfma_f32_32x32x16_bf16(ak1, bq[kc], st1, 0, 0, 0);
      }
      __builtin_amdgcn_s_setprio(0);

      // causal mask: q = qrow0 + l32; t = j*64 + sub*32 + (r&3) + 8*(r>>2) + 4*hi
      if (j * 64 + 63 > qrow0) {
        int qg = qrow0 + l32;
#pragma unroll
        for (int rg = 0; rg < 16; rg++) {
          int t0r = j * 64 + (rg & 3) + 8 * (rg >> 2) + 4 * hi;
          if (t0r > qg)      st0[rg] = -__builtin_inff();
          if (t0r + 32 > qg) st1[rg] = -__builtin_inff();
        }
      }

      // exp2 + row-sum (q-column is lane-local)
#pragma unroll
      for (int rg = 0; rg < 16; rg++) {
        st0[rg] = __builtin_amdgcn_exp2f(st0[rg]);
        st1[rg] = __builtin_amdgcn_exp2f(st1[rg]);
        lsum += st0[rg] + st1[rg];
      }

      // pack P -> PV A-frags: pa[c] holds A[q=l32][t=16c+8hi+j]
      // per sub: L[g][m] = pk(st[4g+2m], st[4g+2m+1]); chunk cl: swap(L[2cl][m], L[2cl+1][m])
      union { unsigned u[4]; bf16x8 v; } pa[4];
#pragma unroll
      for (int sub = 0; sub < 2; sub++) {
        unsigned L0m0 = cvtpk_bf16(sub ? st1[0]  : st0[0],  sub ? st1[1]  : st0[1]);
        unsigned L0m1 = cvtpk_bf16(sub ? st1[2]  : st0[2],  sub ? st1[3]  : st0[3]);
        unsigned L1m0 = cvtpk_bf16(sub ? st1[4]  : st0[4],  sub ? st1[5]  : st0[5]);
        unsigned L1m1 = cvtpk_bf16(sub ? st1[6]  : st0[6],  sub ? st1[7]  : st0[7]);
        unsigned L2m0 = cvtpk_bf16(sub ? st1[8]  : st0[8],  sub ? st1[9]  : st0[9]);
        unsigned L2m1 = cvtpk_bf16(sub ? st1[10] : st0[10], sub ? st1[11] : st0[11]);
        unsigned L3m0 = cvtpk_bf16(sub ? st1[12] : st0[12], sub ? st1[13] : st0[13]);
        unsigned L3m1 = cvtpk_bf16(sub ? st1[14] : st0[14], sub ? st1[15] : st0[15]);
        asm("v_permlane32_swap_b32 %0, %1" : "+v"(L0m0), "+v"(L1m0));
        asm("v_permlane32_swap_b32 %0, %1" : "+v"(L0m1), "+v"(L1m1));
        asm("v_permlane32_swap_b32 %0, %1" : "+v"(L2m0), "+v"(L3m0));
        asm("v_permlane32_swap_b32 %0, %1" : "+v"(L2m1), "+v"(L3m1));
        pa[sub * 2 + 0].u[0] = L0m0; pa[sub * 2 + 0].u[1] = L0m1;
        pa[sub * 2 + 0].u[2] = L1m0; pa[sub * 2 + 0].u[3] = L1m1;
        pa[sub * 2 + 1].u[0] = L2m0; pa[sub * 2 + 1].u[1] = L2m1;
        pa[sub * 2 + 1].u[2] = L3m0; pa[sub * 2 + 1].u[3] = L3m1;
      }

      // PV: O[q][d] two d-halves; B[k=t][n=d] from Vs [d][t] rows
      __builtin_amdgcn_s_setprio(1);
#pragma unroll
      for (int c = 0; c < 4; c++) {
        bf16x8 bv0 = *(const bf16x8*)&Vs[cur][(l32)      * KST + c * 16 + hi * 8];
        bf16x8 bv1 = *(const bf16x8*)&Vs[cur][(32 + l32) * KST + c * 16 + hi * 8];
        oacc0 = __builtin_amdgcn_mfma_f32_32x32x16_bf16(pa[c].v, bv0, oacc0, 0, 0, 0);
        oacc1 = __builtin_amdgcn_mfma_f32_32x32x16_bf16(pa[c].v, bv1, oacc1, 0, 0, 0);
      }
      __builtin_amdgcn_s_setprio(0);
    }

    if (pf) {
      *(uint4*)&Ks[nxt][lr * KST + gcol]     = k0;
      *(uint4*)&Ks[nxt][lr * KST + gcol + 8] = k1;
      *(uint4*)&Vs[nxt][lr * KST + gcol]     = v0;
      *(uint4*)&Vs[nxt][lr * KST + gcol + 8] = v1;
    }
  }

  // combine row-sums across hi halves: every lane ends with total[q=l32]
  {
    union { float f; unsigned u; } a, bcp;
    a.f = lsum; bcp.f = lsum;
    asm("v_permlane32_swap_b32 %0, %1" : "+v"(a.u), "+v"(bcp.u));
    float total = a.f + bcp.f;
    if (hi == 0) Ls[wave][l32] = total;
  }
  __syncthreads();

  // epilogue: q_local(reg r) = (r&3) + 8*(r>>2) + 4*hi; inv from Ls
#pragma unroll
  for (int g = 0; g < 4; g++) {
    f32x4 tv = *(const f32x4*)&Ls[wave][8 * g + 4 * hi];
#pragma unroll
    for (int i = 0; i < 4; i++) {
      int rg = 4 * g + i;
      int tq = qrow0 + 8 * g + 4 * hi + i;
      float inv = 1.f / tv[i];
      unsigned short* yp = &y[((size_t)(b * T_SZ) + tq) * C_SZ + h * HD + l32];
      yp[0]  = f2bf(oacc0[rg] * inv);
      yp[32] = f2bf(oacc1[rg] * inv);
    }
  }
}

extern "C" void kernel_launch(void* const* d_in, const int* in_sizes, int n_in,
                              void* d_out, int out_size, void* d_ws, size_t ws_size,
                              hipStream_t stream) {
  const float* x    = (const float*)d_in[0];
  const float* ve   = (const float*)d_in[1];
  const float* cosb = (const float*)d_in[2];
  const float* sinb = (const float*)d_in[3];
  const float* Wq   = (const float*)d_in[4];
  const float* Wk   = (const float*)d_in[5];
  const float* Wv   = (const float*)d_in[6];
  const float* Wo   = (const float*)d_in[7];
  const float* Wg   = (const float*)d_in[8];
  float* out = (float*)d_out;

  const size_t MB = 1024 * 1024;
  char* ws = (char*)d_ws;
  unsigned short* xb    = (unsigned short*)(ws);             // 8 MB (reused as yb)
  unsigned short* wqkvb = (unsigned short*)(ws + 8 * MB);    // 3 MB
  unsigned short* wob   = (unsigned short*)(ws + 11 * MB);   // 2 MB
  unsigned short* qab   = (unsigned short*)(ws + 13 * MB);   // 8 MB
  unsigned short* kab   = (unsigned short*)(ws + 21 * MB);   // 2 MB
  unsigned short* vtb   = (unsigned short*)(ws + 23 * MB);   // 2 MB
  float*          gateA = (float*)(ws + 25 * MB);            // 64 KB
  unsigned short* yb    = xb;                                // reuse after gemm_qkv

  CvtArgs ca;
  ca.s0 = x;  ca.d0 = xb;
  ca.s1 = Wq; ca.d1 = wqkvb;
  ca.s2 = Wk; ca.d2 = wqkvb + 1024 * 1024;
  ca.s3 = Wv; ca.d3 = wqkvb + 1280 * 1024;
  ca.s4 = Wo; ca.d4 = wob;
  ca.x = x; ca.Wg = Wg; ca.gate = gateA;
  cvt_all<<<6720, 256, 0, stream>>>(ca);

  gemm_qkv<<<dim3(QKV_N / 128, (B_SZ * T_SZ) / 64), 256, 0, stream>>>(
      xb, wqkvb, ve, cosb, sinb, gateA, qab, kab, vtb);

  attn<<<512, 256, 0, stream>>>(qab, kab, vtb, yb);

  gemm_bt<<<dim3(C_SZ / 128, (B_SZ * T_SZ) / 64), 256, 0, stream>>>(
      yb, wob, out, C_SZ, C_SZ);
}

// Round 9
// 161.356 us; speedup vs baseline: 1.0165x; 1.0165x over previous
//
#include <hip/hip_runtime.h>
#include <stdint.h>

#define B_SZ 2
#define T_SZ 2048
#define C_SZ 1024
#define NH   16
#define NKV  4
#define HD   64
#define KVD  256
#define QKV_N 1536

typedef __attribute__((ext_vector_type(8))) short bf16x8;
typedef __attribute__((ext_vector_type(4))) float f32x4;

#define GL(p) ((const __attribute__((address_space(1))) void*)(p))
#define LD(p) ((__attribute__((address_space(3))) void*)(p))

__device__ inline unsigned short f2bf(float f) {
  union { float f; unsigned u; } v; v.f = f;
  unsigned u = v.u;
  unsigned r = (u + 0x7fffu + ((u >> 16) & 1u)) >> 16;
  return (unsigned short)r;
}
__device__ inline unsigned short bftrunc(float f) {  // truncate: 1 inst; bias cancels in O/l
  union { float f; unsigned u; } v; v.f = f;
  return (unsigned short)(v.u >> 16);
}

// ---------------- fused fp32->bf16 convert (5 segments) + gate precompute, 1 launch ----------------
struct CvtArgs {
  const float *s0, *s1, *s2, *s3, *s4;
  unsigned short *d0, *d1, *d2, *d3, *d4;
  const float *x, *Wg;
  float *gate;           // [B*T][NKV]
};
__global__ __launch_bounds__(256) void cvt_all(CvtArgs a) {
  int blk = blockIdx.x, tid = threadIdx.x;
  if (blk >= 6656) {  // gate: 3*sigmoid(x[:, :12] @ Wg^T)
    int idx = (blk - 6656) * 256 + tid;
    int bt = idx >> 2, kh = idx & 3;
    float s = 0.f;
#pragma unroll
    for (int j = 0; j < 12; j++) s += a.x[(size_t)bt * C_SZ + j] * a.Wg[kh * 12 + j];
    a.gate[idx] = 3.f / (1.f + __expf(-s));
    return;
  }
  const float* s; unsigned short* d; int i;
  if      (blk < 4096) { s = a.s0; d = a.d0; i = blk * 256 + tid; }
  else if (blk < 5120) { s = a.s1; d = a.d1; i = (blk - 4096) * 256 + tid; }
  else if (blk < 5376) { s = a.s2; d = a.d2; i = (blk - 5120) * 256 + tid; }
  else if (blk < 5632) { s = a.s3; d = a.d3; i = (blk - 5376) * 256 + tid; }
  else                 { s = a.s4; d = a.d4; i = (blk - 5632) * 256 + tid; }
  float4 f = ((const float4*)s)[i];
  ushort4 o;
  o.x = f2bf(f.x); o.y = f2bf(f.y); o.z = f2bf(f.z); o.w = f2bf(f.w);
  ((ushort4*)d)[i] = o;
}

// ========== GEMM core: 64x128 tile, BK=64, single-barrier ping-pong dbuf, XOR-swizzled LDS ==========
// (round-0 proven config: 768/512 blocks -> 3/2 blocks/CU co-residency hides barrier drain)
#define GEMM_PROLOG(A, Bm, K)                                                        \
  __shared__ unsigned short As[2][64 * 64];                                          \
  __shared__ unsigned short Bs[2][128 * 64];                                         \
  int tid  = threadIdx.x;                                                            \
  int lane = tid & 63;                                                               \
  int wave = tid >> 6;                                                               \
  int quad = lane >> 4;                                                              \
  int l16  = lane & 15;                                                              \
  int m0 = blockIdx.y * 64;                                                          \
  int n0 = blockIdx.x * 128;                                                         \
  int wm = (wave & 1) * 32;                                                          \
  int wn = (wave >> 1) * 64;                                                         \
  f32x4 acc[2][4];                                                                   \
  _Pragma("unroll") for (int i = 0; i < 2; i++)                                      \
    _Pragma("unroll") for (int j = 0; j < 4; j++)                                    \
      acc[i][j] = (f32x4){0.f, 0.f, 0.f, 0.f};                                       \
  int lrow = lane >> 3;                              /* 0..7 within 8-row block */   \
  int lcol = ((lane & 7) ^ lrow) * 8;                /* XOR-swizzled source chunk */ \
  int sA = wave * 16;                                                                \
  int sB = wave * 32;                                                                \
  const unsigned short* aP0 = &A[(size_t)(m0 + sA + lrow) * K + lcol];               \
  const unsigned short* aP1 = aP0 + 8 * (size_t)K;                                   \
  const unsigned short* bP0 = &Bm[(size_t)(n0 + sB + lrow) * K + lcol];              \
  const unsigned short* bP1 = bP0 + 8 * (size_t)K;                                   \
  const unsigned short* bP2 = bP0 + 16 * (size_t)K;                                  \
  const unsigned short* bP3 = bP0 + 24 * (size_t)K;                                  \
  __builtin_amdgcn_global_load_lds(GL(aP0), LD(&As[0][(sA     ) * 64]), 16, 0, 0);   \
  __builtin_amdgcn_global_load_lds(GL(aP1), LD(&As[0][(sA +  8) * 64]), 16, 0, 0);   \
  __builtin_amdgcn_global_load_lds(GL(bP0), LD(&Bs[0][(sB     ) * 64]), 16, 0, 0);   \
  __builtin_amdgcn_global_load_lds(GL(bP1), LD(&Bs[0][(sB +  8) * 64]), 16, 0, 0);   \
  __builtin_amdgcn_global_load_lds(GL(bP2), LD(&Bs[0][(sB + 16) * 64]), 16, 0, 0);   \
  __builtin_amdgcn_global_load_lds(GL(bP3), LD(&Bs[0][(sB + 24) * 64]), 16, 0, 0);   \
  int swz = l16 & 7;                                                                 \
  int nk = K >> 6;                                                                   \
  for (int ki = 0; ki < nk; ki++) {                                                  \
    int cur = ki & 1, nxt = cur ^ 1;                                                 \
    __syncthreads();                                                                 \
    if (ki + 1 < nk) {                                                               \
      int k0 = (ki + 1) << 6;                                                        \
      __builtin_amdgcn_global_load_lds(GL(aP0 + k0), LD(&As[nxt][(sA     ) * 64]), 16, 0, 0); \
      __builtin_amdgcn_global_load_lds(GL(aP1 + k0), LD(&As[nxt][(sA +  8) * 64]), 16, 0, 0); \
      __builtin_amdgcn_global_load_lds(GL(bP0 + k0), LD(&Bs[nxt][(sB     ) * 64]), 16, 0, 0); \
      __builtin_amdgcn_global_load_lds(GL(bP1 + k0), LD(&Bs[nxt][(sB +  8) * 64]), 16, 0, 0); \
      __builtin_amdgcn_global_load_lds(GL(bP2 + k0), LD(&Bs[nxt][(sB + 16) * 64]), 16, 0, 0); \
      __builtin_amdgcn_global_load_lds(GL(bP3 + k0), LD(&Bs[nxt][(sB + 24) * 64]), 16, 0, 0); \
    }                                                                                \
    _Pragma("unroll") for (int p = 0; p < 2; p++) {                                  \
      bf16x8 af[2], bfr[4];                                                          \
      _Pragma("unroll") for (int i = 0; i < 2; i++)                                  \
        af[i] = *(const bf16x8*)&As[cur][(wm + i * 16 + l16) * 64 + (((p * 4 + quad) ^ swz) * 8)]; \
      _Pragma("unroll") for (int j = 0; j < 4; j++)                                  \
        bfr[j] = *(const bf16x8*)&Bs[cur][(wn + j * 16 + l16) * 64 + (((p * 4 + quad) ^ swz) * 8)]; \
      _Pragma("unroll") for (int i = 0; i < 2; i++)                                  \
        _Pragma("unroll") for (int j = 0; j < 4; j++)                                \
          acc[i][j] = __builtin_amdgcn_mfma_f32_16x16x32_bf16(af[i], bfr[j], acc[i][j], 0, 0, 0); \
    }                                                                                \
  }

// ---------------- gemm2: C[m,n] = sum_k A[m,k]*B[n,k], fp32 out ----------------
__global__ __launch_bounds__(256) void gemm_bt(const unsigned short* __restrict__ A,
                                               const unsigned short* __restrict__ Bm,
                                               float* __restrict__ C,
                                               int N, int K) {
  GEMM_PROLOG(A, Bm, K)
#pragma unroll
  for (int i = 0; i < 2; i++) {
#pragma unroll
    for (int j = 0; j < 4; j++) {
      int col = n0 + wn + j * 16 + l16;
#pragma unroll
      for (int r = 0; r < 4; r++) {
        int row = m0 + wm + i * 16 + quad * 4 + r;
        C[(size_t)row * N + col] = acc[i][j][r];
      }
    }
  }
}

// ---------------- gemm1 fused: qkv proj + RoPE + RMSNorm + gate*ve + V-TRANSPOSE, bf16 out ----------
// Q/K heads: RoPE+RMS epilogue. V blocks (n0>=1280, whole block is V): epilogue transposes the
// 64(bt) x 128(2 heads) tile through LDS (reusing Bs[0]: last K-iter reads only buffers [1])
// and writes vt (B,NKV,HD,T) directly -> v_transpose kernel + vtmp eliminated.
__global__ __launch_bounds__(256) void gemm_qkv(const unsigned short* __restrict__ A,
                                                const unsigned short* __restrict__ Bm,
                                                const float* __restrict__ ve,
                                                const float* __restrict__ cosb,
                                                const float* __restrict__ sinb,
                                                const float* __restrict__ gateArr,
                                                unsigned short* __restrict__ qa,
                                                unsigned short* __restrict__ ka,
                                                unsigned short* __restrict__ vt) {
  const int K = C_SZ;
  GEMM_PROLOG(A, Bm, K)

  int colbase = n0 + wn;   // multiple of 64
  if (colbase < 1280) {    // Q or K head
    int isQ = colbase < 1024;
    int h   = isQ ? (colbase >> 6) : ((colbase - 1024) >> 6);
    float scale = isQ ? (0.15f * 1.44269504088896f) : 1.2f;
    unsigned short* dst = isQ ? qa : ka;
    int nheads = isQ ? NH : NKV;
#pragma unroll
    for (int i = 0; i < 2; i++) {
#pragma unroll
      for (int r = 0; r < 4; r++) {
        int row = m0 + wm + i * 16 + quad * 4 + r;   // bt
        int t = row & (T_SZ - 1), b = row >> 11;
        float a10 = acc[i][0][r], a11 = acc[i][1][r];
        float a20 = acc[i][2][r], a21 = acc[i][3][r];
        float cv0 = cosb[t * 32 + l16],      sv0 = sinb[t * 32 + l16];
        float cv1 = cosb[t * 32 + 16 + l16], sv1 = sinb[t * 32 + 16 + l16];
        float o10 =  a10 * cv0 + a20 * sv0;
        float o11 =  a11 * cv1 + a21 * sv1;
        float o20 = -a10 * sv0 + a20 * cv0;
        float o21 = -a11 * sv1 + a21 * cv1;
        float ssq = o10 * o10 + o11 * o11 + o20 * o20 + o21 * o21;
        ssq += __shfl_xor(ssq, 1);
        ssq += __shfl_xor(ssq, 2);
        ssq += __shfl_xor(ssq, 4);
        ssq += __shfl_xor(ssq, 8);
        float rn = rsqrtf(ssq * (1.f / 64.f) + 1e-6f) * scale;
        size_t base = ((size_t)(b * nheads + h) * T_SZ + t) * HD;
        dst[base + l16]      = f2bf(o10 * rn);
        dst[base + 16 + l16] = f2bf(o11 * rn);
        dst[base + 32 + l16] = f2bf(o20 * rn);
        dst[base + 48 + l16] = f2bf(o21 * rn);
      }
    }
  } else {                 // V block: gate*ve add, transpose via LDS, write vt directly
    int kh  = (colbase - 1280) >> 6;                 // this wave's head
    int khb = (n0 - 1280) >> 6;                      // block's base head
    unsigned short* tile = (unsigned short*)&Bs[0][0];   // 64 x 128, stride 132
    const int TS = 132;
    // phase 1: write [t_local][d2]; lanes: l16 contiguous (2/bank), quads 8 banks apart -> clean
#pragma unroll
    for (int i = 0; i < 2; i++) {
#pragma unroll
      for (int r = 0; r < 4; r++) {
        int rl  = wm + i * 16 + quad * 4 + r;        // t_local 0..63
        int row = m0 + rl;                           // bt
        float g = gateArr[row * 4 + kh];
#pragma unroll
        for (int j = 0; j < 4; j++) {
          int d = j * 16 + l16;
          float val = acc[i][j][r] + g * ve[(size_t)row * KVD + kh * HD + d];
          tile[rl * TS + wn + d] = f2bf(val);
        }
      }
    }
    __syncthreads();
    // phase 2: column gather (64 lanes span 128B -> 32 banks 2-way = free), coalesced vt rows
    int d2  = tid & 127;                             // 0..127 across both heads
    int seg = tid >> 7;                              // t half: 0,1
    int khw = khb + (d2 >> 6);
    int dd  = d2 & 63;
    int bb  = m0 >> 11;
    int tl0 = (m0 & (T_SZ - 1)) + seg * 32;
    unsigned short* dstp = &vt[((size_t)(bb * NKV + khw) * HD + dd) * T_SZ + tl0];
#pragma unroll
    for (int k4 = 0; k4 < 8; k4++) {
      ushort4 o;
      o.x = tile[(seg * 32 + k4 * 4 + 0) * TS + d2];
      o.y = tile[(seg * 32 + k4 * 4 + 1) * TS + d2];
      o.z = tile[(seg * 32 + k4 * 4 + 2) * TS + d2];
      o.w = tile[(seg * 32 + k4 * 4 + 3) * TS + d2];
      *(ushort4*)(dstp + k4 * 4) = o;
    }
  }
}

// ---------------- causal flash attention: Q=128, 8 waves x 16 q-rows, S^T trick ----------------
// Measured-best structure (r3/r7): dbuf single barrier, 512 threads, 16 waves/CU,
// s_setprio(1) around MFMA clusters. Empirical floor across 6 structural variants (~35 us).
#define KST 72
#define PST 72
__global__ __launch_bounds__(512, 4) void attn(const unsigned short* __restrict__ qa,
                                               const unsigned short* __restrict__ ka,
                                               const unsigned short* __restrict__ vt,
                                               unsigned short* __restrict__ y) {
  // pair qt with 15-qt so co-resident blocks sum to equal work
  int bid = blockIdx.x;
  int half = bid >> 8, r = bid & 255;
  int qt = half ? (r & 15) : 15 - (r & 15);
  int bh = (half << 4) | (r >> 4);
  int b = bh >> 4, h = bh & 15;
  int kh = h >> 2;
  int tid = threadIdx.x;
  int wave = tid >> 6, lane = tid & 63;
  int quad = lane >> 4, l16 = lane & 15;

  __shared__ unsigned short Ks[2][64 * KST];   // [t_local][d]
  __shared__ unsigned short Vs[2][64 * KST];   // [d][t_local]
  __shared__ unsigned short Ps[128 * PST];     // [q_local][t_local]
  unsigned short* Pw = &Ps[(wave * 16) * PST];

  int qrow0 = qt * 128 + wave * 16;

  bf16x8 bq0, bq1;
  {
    int tq = qrow0 + l16;
    const unsigned short* qp = &qa[((size_t)(b * NH + h) * T_SZ + tq) * HD];
    bq0 = *(const bf16x8*)&qp[quad * 8];
    bq1 = *(const bf16x8*)&qp[32 + quad * 8];
  }

  const unsigned short one_bf = 0x3F80;
  bf16x8 vones = {(short)one_bf, (short)one_bf, (short)one_bf, (short)one_bf,
                  (short)one_bf, (short)one_bf, (short)one_bf, (short)one_bf};

  f32x4 oacc[4];
  f32x4 lacc = (f32x4){0.f, 0.f, 0.f, 0.f};
#pragma unroll
  for (int d = 0; d < 4; d++) oacc[d] = (f32x4){0.f, 0.f, 0.f, 0.f};

  int lr = tid >> 3;          // 0..63
  int lc = (tid & 7) * 8;     // 0..56 step 8

  const unsigned short* kbase = &ka[(size_t)(b * NKV + kh) * T_SZ * HD];
  const unsigned short* vbase = &vt[(size_t)(b * NKV + kh) * HD * T_SZ];

  int nj = 2 * qt + 2;

  {
    uint4 k0 = *(const uint4*)&kbase[(size_t)lr * HD + lc];
    uint4 v0 = *(const uint4*)&vbase[(size_t)lr * T_SZ + lc];
    *(uint4*)&Ks[0][lr * KST + lc] = k0;
    *(uint4*)&Vs[0][lr * KST + lc] = v0;
  }

  for (int j = 0; j < nj; j++) {
    int cur = j & 1, nxt = cur ^ 1;
    __syncthreads();   // buf[cur] writes visible; all prior reads drained

    uint4 k0, v0;
    bool pf = (j + 1 < nj);
    if (pf) {
      k0 = *(const uint4*)&kbase[(size_t)((j + 1) * 64 + lr) * HD + lc];
      v0 = *(const uint4*)&vbase[(size_t)lr * T_SZ + (j + 1) * 64 + lc];
    }

    // waves whose 16 q-rows all precede this K-block are fully masked -> skip compute
    bool active = (j * 64) <= (qrow0 + 15);

    if (active) {
      // S^T = K Q^T: D[m=t][n=q]; K-frags as A
      f32x4 st[4];
      __builtin_amdgcn_s_setprio(1);
#pragma unroll
      for (int tb = 0; tb < 4; tb++) {
        bf16x8 ak0 = *(const bf16x8*)&Ks[cur][(tb * 16 + l16) * KST + quad * 8];
        bf16x8 ak1 = *(const bf16x8*)&Ks[cur][(tb * 16 + l16) * KST + 32 + quad * 8];
        f32x4 s = (f32x4){0.f, 0.f, 0.f, 0.f};
        s = __builtin_amdgcn_mfma_f32_16x16x32_bf16(ak0, bq0, s, 0, 0, 0);
        s = __builtin_amdgcn_mfma_f32_16x16x32_bf16(ak1, bq1, s, 0, 0, 0);
        st[tb] = s;
      }
      __builtin_amdgcn_s_setprio(0);

      // mask + exp2 + packed b64 store of P[q][t] (per-wave region, no barrier needed)
      if (j * 64 + 63 > qrow0) {
        int qg = qrow0 + l16;
#pragma unroll
        for (int tb = 0; tb < 4; tb++) {
          int tg = j * 64 + tb * 16 + quad * 4;
#pragma unroll
          for (int i = 0; i < 4; i++) {
            if (tg + i > qg) st[tb][i] = -__builtin_inff();
          }
        }
      }
#pragma unroll
      for (int tb = 0; tb < 4; tb++) {
        ushort4 w;
        w.x = bftrunc(__builtin_amdgcn_exp2f(st[tb][0]));
        w.y = bftrunc(__builtin_amdgcn_exp2f(st[tb][1]));
        w.z = bftrunc(__builtin_amdgcn_exp2f(st[tb][2]));
        w.w = bftrunc(__builtin_amdgcn_exp2f(st[tb][3]));
        *(ushort4*)&Pw[l16 * PST + tb * 16 + quad * 4] = w;
      }

      bf16x8 ap0 = *(const bf16x8*)&Pw[l16 * PST + quad * 8];
      bf16x8 ap1 = *(const bf16x8*)&Pw[l16 * PST + 32 + quad * 8];
      __builtin_amdgcn_s_setprio(1);
      lacc = __builtin_amdgcn_mfma_f32_16x16x32_bf16(ap0, vones, lacc, 0, 0, 0);
      lacc = __builtin_amdgcn_mfma_f32_16x16x32_bf16(ap1, vones, lacc, 0, 0, 0);
#pragma unroll
      for (int d = 0; d < 4; d++) {
        bf16x8 bv0 = *(const bf16x8*)&Vs[cur][(d * 16 + l16) * KST + quad * 8];
        bf16x8 bv1 = *(const bf16x8*)&Vs[cur][(d * 16 + l16) * KST + 32 + quad * 8];
        oacc[d] = __builtin_amdgcn_mfma_f32_16x16x32_bf16(ap0, bv0, oacc[d], 0, 0, 0);
        oacc[d] = __builtin_amdgcn_mfma_f32_16x16x32_bf16(ap1, bv1, oacc[d], 0, 0, 0);
      }
      __builtin_amdgcn_s_setprio(0);
    }

    if (pf) {
      *(uint4*)&Ks[nxt][lr * KST + lc] = k0;
      *(uint4*)&Vs[nxt][lr * KST + lc] = v0;
    }
  }

#pragma unroll
  for (int i = 0; i < 4; i++) {
    int tq = qrow0 + quad * 4 + i;
    float inv = 1.f / lacc[i];
#pragma unroll
    for (int d = 0; d < 4; d++) {
      y[((size_t)(b * T_SZ) + tq) * C_SZ + h * HD + d * 16 + l16] = f2bf(oacc[d][i] * inv);
    }
  }
}

extern "C" void kernel_launch(void* const* d_in, const int* in_sizes, int n_in,
                              void* d_out, int out_size, void* d_ws, size_t ws_size,
                              hipStream_t stream) {
  const float* x    = (const float*)d_in[0];
  const float* ve   = (const float*)d_in[1];
  const float* cosb = (const float*)d_in[2];
  const float* sinb = (const float*)d_in[3];
  const float* Wq   = (const float*)d_in[4];
  const float* Wk   = (const float*)d_in[5];
  const float* Wv   = (const float*)d_in[6];
  const float* Wo   = (const float*)d_in[7];
  const float* Wg   = (const float*)d_in[8];
  float* out = (float*)d_out;

  const size_t MB = 1024 * 1024;
  char* ws = (char*)d_ws;
  unsigned short* xb    = (unsigned short*)(ws);             // 8 MB (reused as yb)
  unsigned short* wqkvb = (unsigned short*)(ws + 8 * MB);    // 3 MB
  unsigned short* wob   = (unsigned short*)(ws + 11 * MB);   // 2 MB
  unsigned short* qab   = (unsigned short*)(ws + 13 * MB);   // 8 MB
  unsigned short* kab   = (unsigned short*)(ws + 21 * MB);   // 2 MB
  unsigned short* vtb   = (unsigned short*)(ws + 23 * MB);   // 2 MB
  float*          gateA = (float*)(ws + 25 * MB);            // 64 KB
  unsigned short* yb    = xb;                                // reuse after gemm_qkv

  CvtArgs ca;
  ca.s0 = x;  ca.d0 = xb;
  ca.s1 = Wq; ca.d1 = wqkvb;
  ca.s2 = Wk; ca.d2 = wqkvb + 1024 * 1024;
  ca.s3 = Wv; ca.d3 = wqkvb + 1280 * 1024;
  ca.s4 = Wo; ca.d4 = wob;
  ca.x = x; ca.Wg = Wg; ca.gate = gateA;
  cvt_all<<<6720, 256, 0, stream>>>(ca);

  gemm_qkv<<<dim3(QKV_N / 128, (B_SZ * T_SZ) / 64), 256, 0, stream>>>(
      xb, wqkvb, ve, cosb, sinb, gateA, qab, kab, vtb);

  attn<<<512, 512, 0, stream>>>(qab, kab, vtb, yb);

  gemm_bt<<<dim3(C_SZ / 128, (B_SZ * T_SZ) / 64), 256, 0, stream>>>(
      yb, wob, out, C_SZ, C_SZ);
}